// Round 12
// baseline (339.662 us; speedup 1.0000x reference)
//
#include <hip/hip_runtime.h>
#include <math.h>

#define B 16
#define CIN 512
#define COUT 512
#define SDIM 512
#define H 64
#define W 64

typedef short s16x8 __attribute__((ext_vector_type(8)));
typedef float f32x4 __attribute__((ext_vector_type(4)));
typedef float f32x16 __attribute__((ext_vector_type(16)));

__device__ __constant__ float LIN_SCALE  = 0.04419417382415922f;   // 1/sqrt(512)
__device__ __constant__ float CONV_SCALE = 0.014731391274719742f;  // 1/sqrt(512*9)

__device__ __forceinline__ ushort f2bf(float f) {
  unsigned u = __float_as_uint(f);
  return (ushort)((u + 0x7FFFu + ((u >> 16) & 1u)) >> 16);  // RNE
}

#define GLOAD16(g, l)                                           \
  __builtin_amdgcn_global_load_lds(                             \
      (const __attribute__((address_space(1))) unsigned*)(g),   \
      (__attribute__((address_space(3))) unsigned*)(l), 16, 0, 0)

// ---------------------------------------------------------------------------
// K1: blocks 0..511 pack_w (+wsq), one ci-PAIR per thread (131072 units);
//     blocks 512..527 style-mod (s, s2).
// wt layout: wt[chunk32][cb8][j9][oct2][co64][8ci] bf16
//   ushort strides: chunk 73728, cb 9216, j 1024, oct 512, co 8
// ---------------------------------------------------------------------------
__global__ __launch_bounds__(256) void prep1_kernel(
    const float* __restrict__ w, const float* __restrict__ style,
    const float* __restrict__ style_w, const float* __restrict__ style_b,
    ushort* __restrict__ wt, float* __restrict__ wsq, float* __restrict__ s,
    float* __restrict__ s2) {
  const int tid = threadIdx.x;
  if (blockIdx.x < 512) {
    const int u = blockIdx.x * 256 + tid;  // 131072 units
    const int e = u & 7;                   // ci-pair index (ci = 2e)
    const int chunk = (u >> 3) & 31;
    const int co = u >> 8;
    // 18 floats = taps of ci 2e, 2e+1 ; base is even -> float2 aligned
    const float2* wp = (const float2*)(
        w + ((size_t)co * 512 + chunk * 16 + e * 2) * 9);
    float wv[18];
#pragma unroll
    for (int i = 0; i < 9; ++i) {
      float2 v = wp[i];
      wv[2 * i] = v.x;
      wv[2 * i + 1] = v.y;
    }
    // wsq for the two ci
    {
      float q0 = 0.f, q1 = 0.f;
#pragma unroll
      for (int k = 0; k < 9; ++k) {
        q0 += wv[k] * wv[k];
        q1 += wv[9 + k] * wv[9 + k];
      }
      *(float2*)(wsq + (size_t)co * 512 + chunk * 16 + e * 2) =
          make_float2(q0, q1);
    }
    const int cb = co >> 6, co64 = co & 63;
    ushort* dst = wt + (size_t)chunk * 73728 + (size_t)cb * 9216 +
                  (size_t)(e >> 2) * 512 + (size_t)co64 * 8 + (e & 3) * 2;
#pragma unroll
    for (int j = 0; j < 9; ++j) {
      unsigned pk = (unsigned)f2bf(wv[j]) | ((unsigned)f2bf(wv[9 + j]) << 16);
      *(unsigned*)(dst + (size_t)j * 1024) = pk;
    }
  } else {
    const int bb = blockIdx.x - 512;
    __shared__ float st[SDIM];
    st[tid] = style[bb * SDIM + tid];
    st[tid + 256] = style[bb * SDIM + tid + 256];
    __syncthreads();
#pragma unroll
    for (int half = 0; half < 2; ++half) {
      const int ci = tid + half * 256;
      const float4* wr =
          reinterpret_cast<const float4*>(style_w + (size_t)ci * SDIM);
      float acc = 0.f;
#pragma unroll 4
      for (int k = 0; k < SDIM / 4; ++k) {
        float4 wv = wr[k];
        acc += st[4 * k + 0] * wv.x + st[4 * k + 1] * wv.y +
               st[4 * k + 2] * wv.z + st[4 * k + 3] * wv.w;
      }
      float v = acc * LIN_SCALE + style_b[ci];
      s[bb * CIN + ci] = v;
      s2[bb * CIN + ci] = v * v;
    }
  }
}

// ---------------------------------------------------------------------------
// K2: blocks 0..16383 pack_x (s folded, CB16 octet-major);
//     blocks 16384..16399 dcoef (hidden under pack_x).
//   xp[b][chunk32][oct2][gr64][col64][8ci] bf16
//   ushort strides: b 2097152, chunk 65536, oct 32768, gr 512, col 8
//   decode: gr = blk&63, cp = (blk>>6)&15, b = blk>>10   (16384 = 64*16*16)
// ---------------------------------------------------------------------------
__global__ __launch_bounds__(256) void prep2_kernel(
    const float* __restrict__ x, const float* __restrict__ smod,
    const float* __restrict__ s2, const float* __restrict__ wsq,
    ushort* __restrict__ xp, float* __restrict__ outscale) {
  const int tid = threadIdx.x;
  if (blockIdx.x < 16384) {
    const int blk = blockIdx.x;
    const int gr = blk & 63, cp = (blk >> 6) & 15, b = blk >> 10;
    __shared__ float xt[32][65];
    __shared__ float sm[32];
    if (tid < 32) sm[tid] = smod[b * 512 + cp * 32 + tid];
    {
      const int ci = tid >> 3, cq = tid & 7;
      const float4* rp = (const float4*)(
          x + (((size_t)b * 512 + cp * 32 + ci) * 64 + gr) * 64 + cq * 8);
      float4 a = rp[0], c2 = rp[1];
      float* row = &xt[ci][cq * 8];
      row[0] = a.x; row[1] = a.y; row[2] = a.z; row[3] = a.w;
      row[4] = c2.x; row[5] = c2.y; row[6] = c2.z; row[7] = c2.w;
    }
    __syncthreads();
    const int c = tid & 63, o = tid >> 6;  // col, ci-octet-of-32 (0..3)
    s16x8 p;
#pragma unroll
    for (int i = 0; i < 8; ++i)
      p[i] = (short)f2bf(xt[o * 8 + i][c] * sm[o * 8 + i]);
    const int chunk = cp * 2 + (o >> 1), oct = o & 1;
    *(s16x8*)(xp + (size_t)b * 2097152 + (size_t)chunk * 65536 +
              oct * 32768 + gr * 512 + c * 8) = p;
  } else {
    const int b = blockIdx.x - 16384;
    __shared__ float sh[CIN];
    sh[tid] = s2[b * CIN + tid];
    sh[tid + 256] = s2[b * CIN + tid + 256];
    __syncthreads();
#pragma unroll
    for (int half = 0; half < 2; ++half) {
      const int co = tid + half * 256;
      const float4* wr =
          reinterpret_cast<const float4*>(wsq + (size_t)co * CIN);
      float acc = 0.f;
#pragma unroll 4
      for (int k = 0; k < CIN / 4; ++k) {
        float4 wv = wr[k];
        acc += sh[4 * k + 0] * wv.x + sh[4 * k + 1] * wv.y +
               sh[4 * k + 2] * wv.z + sh[4 * k + 3] * wv.w;
      }
      float d = rsqrtf(acc * CONV_SCALE * CONV_SCALE + 1e-8f);
      outscale[b * COUT + co] = d * CONV_SCALE;
    }
  }
}

// ---------------------------------------------------------------------------
// Kernel 9 (unchanged, proven 242 us): dbuf-prefetch 32x32x16 MFMA conv,
// CB=16, 2 blocks/CU, octet-major dense LDS (0 conflicts).
// ---------------------------------------------------------------------------
#define CBUF_WS 18432
#define CBUF_XS 21120
#define XS_BASE 36864
#define DLDS9 79104

__global__ __launch_bounds__(256, 2) void conv_mfma9_kernel(
    const ushort* __restrict__ wt, const ushort* __restrict__ xp,
    const float* __restrict__ outscale, float* __restrict__ out) {
  extern __shared__ char smem[];

  const int tid = threadIdx.x;
  const int hb = blockIdx.x;  // 0..7
  const int cb = blockIdx.y;  // 0..7
  const int b  = blockIdx.z;  // 0..15
  const int h0 = hb * 8, co0 = cb * 64;
  const int lane = tid & 63, wid = tid >> 6;  // 4 waves
  const int l31 = lane & 31, hi = lane >> 5;

  {
    s16x8* p = (s16x8*)(smem + XS_BASE);
    for (int e = tid; e < 2640; e += 256) p[e] = (s16x8)0;
  }

  f32x16 acc[2][2][2];
#pragma unroll
  for (int rr = 0; rr < 2; ++rr)
#pragma unroll
    for (int mt = 0; mt < 2; ++mt)
#pragma unroll
      for (int nt = 0; nt < 2; ++nt) acc[rr][mt][nt] = (f32x16)0.f;

  int aoff[2];
#pragma unroll
  for (int mt = 0; mt < 2; ++mt)
    aoff[mt] = hi * 1024 + (mt * 32 + l31) * 16;
  int boff[3][2];
#pragma unroll
  for (int kw = 0; kw < 3; ++kw)
#pragma unroll
    for (int nt = 0; nt < 2; ++nt)
      boff[kw][nt] = hi * 10560 + (nt * 32 + l31 + kw) * 16;

  const char* wsrc0 = (const char*)wt + (size_t)cb * 18432;
  const char* xsrc0 = (const char*)xp + (size_t)b * 4194304;

  auto stage = [&](int chunk, int buf) {
    const char* wsrc = wsrc0 + (size_t)chunk * 147456;
    const char* xsrc = xsrc0 + (size_t)chunk * 131072;
    char* wd = smem + buf * CBUF_WS;
    char* xd = smem + XS_BASE + buf * CBUF_XS;
#pragma unroll
    for (int p = 0; p < 4; ++p)
      GLOAD16(wsrc + p * 4096 + tid * 16, wd + p * 4096 + tid * 16);
    if (tid < 128)
      GLOAD16(wsrc + 16384 + tid * 16, wd + 16384 + tid * 16);
#pragma unroll
    for (int p = 0; p < 5; ++p) {
      int e = p * 4 + wid;  // 0..19 = (oct, row)
      int oct = (e >= 10) ? 1 : 0;
      int r = e - oct * 10;
      int gr = h0 - 1 + r;
      if ((unsigned)gr < 64u)
        GLOAD16(xsrc + oct * 65536 + gr * 1024 + lane * 16,
                xd + oct * 10560 + r * 1056 + 16 + lane * 16);
    }
  };

  auto compute = [&](int buf) {
    const char* wb2 = smem + buf * CBUF_WS;
    const char* xb2 = smem + XS_BASE + buf * CBUF_XS + 2 * wid * 1056;
#pragma unroll
    for (int kw = 0; kw < 3; ++kw) {
      s16x8 bf[4][2];  // rows 2wid..2wid+3, cached across kh
#pragma unroll
      for (int q = 0; q < 4; ++q)
#pragma unroll
        for (int nt = 0; nt < 2; ++nt)
          bf[q][nt] = *(const s16x8*)(xb2 + q * 1056 + boff[kw][nt]);
#pragma unroll
      for (int kh = 0; kh < 3; ++kh) {
        const char* wj = wb2 + (kh * 3 + kw) * 2048;
        s16x8 af0 = *(const s16x8*)(wj + aoff[0]);
        s16x8 af1 = *(const s16x8*)(wj + aoff[1]);
#pragma unroll
        for (int rr = 0; rr < 2; ++rr)
#pragma unroll
          for (int nt = 0; nt < 2; ++nt) {
            acc[rr][0][nt] = __builtin_amdgcn_mfma_f32_32x32x16_bf16(
                af0, bf[rr + kh][nt], acc[rr][0][nt], 0, 0, 0);
            acc[rr][1][nt] = __builtin_amdgcn_mfma_f32_32x32x16_bf16(
                af1, bf[rr + kh][nt], acc[rr][1][nt], 0, 0, 0);
          }
      }
    }
  };

  __syncthreads();  // zeros visible
  stage(0, 0);

  for (int c = 0; c < 32; ++c) {
    const int buf = c & 1;
    __syncthreads();  // drains stage(c) (issued a full chunk ago -> ~free);
                      // also: all waves done reading buf^1 (chunk c-1)
    if (c + 1 < 32) stage(c + 1, buf ^ 1);
    compute(buf);
  }

  // epilogue: D col(px)=l31, row(co)=(reg&3)+8*(reg>>2)+4*hi
#pragma unroll
  for (int mt = 0; mt < 2; ++mt) {
#pragma unroll
    for (int reg = 0; reg < 16; ++reg) {
      const int row = (reg & 3) + 8 * (reg >> 2) + 4 * hi;
      const int co = co0 + mt * 32 + row;
      const float osc = outscale[b * COUT + co];
      float* obase = out + ((size_t)b * COUT + co) * H * W;
#pragma unroll
      for (int rr = 0; rr < 2; ++rr) {
        const int h = h0 + 2 * wid + rr;
#pragma unroll
        for (int nt = 0; nt < 2; ++nt)
          obase[h * W + nt * 32 + l31] = acc[rr][mt][nt][reg] * osc;
      }
    }
  }
}

// ---------------------------------------------------------------------------
// Fallback conv (R2, proven, packless): raw x/weight/s inputs, ~630 us.
// ---------------------------------------------------------------------------
__global__ __launch_bounds__(256, 2) void conv_mfma_kernel(
    const float* __restrict__ x, const float* __restrict__ weight,
    const float* __restrict__ s, const float* __restrict__ outscale,
    float* __restrict__ out) {
  __shared__ ushort xs[6][66][32];
  __shared__ ushort ws[9][64][32];

  const int tid = threadIdx.x;
  const int hb = blockIdx.x;
  const int cb = blockIdx.y;
  const int b  = blockIdx.z;
  const int h0 = hb * 4;
  const int co0 = cb * 64;
  const int lane = tid & 63;
  const int wid = tid >> 6;
  const int l15 = lane & 15;
  const int l4  = lane >> 4;

  f32x4 acc[4][4];
#pragma unroll
  for (int mt = 0; mt < 4; ++mt)
#pragma unroll
    for (int nt = 0; nt < 4; ++nt) acc[mt][nt] = (f32x4)0.f;

  const int wq = tid & 3;
  const int wco = tid >> 2;

  for (int c0 = 0; c0 < CIN; c0 += 32) {
    {
      const float4* wp = reinterpret_cast<const float4*>(
          weight + ((size_t)(co0 + wco) * CIN + c0 + wq * 8) * 9);
      float wv[72];
#pragma unroll
      for (int t = 0; t < 18; ++t) {
        float4 v = wp[t];
        wv[4 * t + 0] = v.x; wv[4 * t + 1] = v.y;
        wv[4 * t + 2] = v.z; wv[4 * t + 3] = v.w;
      }
      float sv[8];
#pragma unroll
      for (int i = 0; i < 8; ++i) sv[i] = s[b * CIN + c0 + wq * 8 + i];
#pragma unroll
      for (int j = 0; j < 9; ++j) {
        s16x8 p;
#pragma unroll
        for (int i = 0; i < 8; ++i)
          p[i] = (short)f2bf(wv[i * 9 + j] * sv[i]);
        *reinterpret_cast<s16x8*>(&ws[j][wco][wq * 8]) = p;
      }
    }
#pragma unroll
    for (int it = 0; it < 7; ++it) {
      int e = tid + it * 256;
      if (e < 6 * 66 * 4) {
        int q = e & 3;
        int t2 = e >> 2;
        int cc = t2 % 66;
        int r = t2 / 66;
        int gr = h0 - 1 + r;
        int gc = cc - 1;
        s16x8 p;
        if ((unsigned)gr < H && (unsigned)gc < W) {
          const float* xp2 =
              x + (((size_t)b * CIN + c0 + q * 8) * H + gr) * W + gc;
#pragma unroll
          for (int i = 0; i < 8; ++i) p[i] = (short)f2bf(xp2[(size_t)i * H * W]);
        } else {
#pragma unroll
          for (int i = 0; i < 8; ++i) p[i] = 0;
        }
        *reinterpret_cast<s16x8*>(&xs[r][cc][q * 8]) = p;
      }
    }
    __syncthreads();

#pragma unroll
    for (int kh = 0; kh < 3; ++kh) {
#pragma unroll
      for (int kw = 0; kw < 3; ++kw) {
        const int j = kh * 3 + kw;
        s16x8 af[4], bf[4];
#pragma unroll
        for (int mt = 0; mt < 4; ++mt)
          af[mt] = *reinterpret_cast<const s16x8*>(
              &ws[j][mt * 16 + l15][l4 * 8]);
#pragma unroll
        for (int nt = 0; nt < 4; ++nt)
          bf[nt] = *reinterpret_cast<const s16x8*>(
              &xs[wid + kh][nt * 16 + l15 + kw][l4 * 8]);
#pragma unroll
        for (int mt = 0; mt < 4; ++mt)
#pragma unroll
          for (int nt = 0; nt < 4; ++nt)
            acc[mt][nt] = __builtin_amdgcn_mfma_f32_16x16x32_bf16(
                af[mt], bf[nt], acc[mt][nt], 0, 0, 0);
      }
    }
    __syncthreads();
  }

  const int h = h0 + wid;
#pragma unroll
  for (int mt = 0; mt < 4; ++mt) {
#pragma unroll
    for (int r = 0; r < 4; ++r) {
      const int co = co0 + mt * 16 + l4 * 4 + r;
      const float osc = outscale[b * COUT + co];
      float* orow = out + (((size_t)b * COUT + co) * H + h) * W;
#pragma unroll
      for (int nt = 0; nt < 4; ++nt)
        orow[nt * 16 + l15] = acc[mt][nt][r] * osc;
    }
  }
}

// ---------------------------------------------------------------------------
extern "C" void kernel_launch(void* const* d_in, const int* in_sizes, int n_in,
                              void* d_out, int out_size, void* d_ws,
                              size_t ws_size, hipStream_t stream) {
  const float* x = (const float*)d_in[0];
  const float* style = (const float*)d_in[1];
  const float* weight = (const float*)d_in[2];
  const float* style_w = (const float*)d_in[3];
  const float* style_b = (const float*)d_in[4];
  float* out = (float*)d_out;

  // workspace layout (bytes):
  //   0        s        (32768)
  //   32768    s2       (32768)
  //   65536    wsq      (1048576)
  //   1114112  outscale (32768)
  //   1146880  wt       (4718592)   packed bf16 weights (CB16 octet-major)
  //   5865472  xp       (67108864)  packed bf16 x (s folded, CB16 octet-major)
  char* wsb = (char*)d_ws;
  float* s = (float*)(wsb + 0);
  float* s2 = (float*)(wsb + 32768);
  float* wsq = (float*)(wsb + 65536);
  float* outscale = (float*)(wsb + 1114112);
  ushort* wt = (ushort*)(wsb + 1146880);
  ushort* xp = (ushort*)(wsb + 5865472);
  const size_t NEED = 72974336;

  hipError_t attr_ok = hipFuncSetAttribute(
      reinterpret_cast<const void*>(conv_mfma9_kernel),
      hipFuncAttributeMaxDynamicSharedMemorySize, DLDS9);

  prep1_kernel<<<528, 256, 0, stream>>>(weight, style, style_w, style_b, wt,
                                        wsq, s, s2);
  if (attr_ok == hipSuccess && ws_size >= NEED) {
    prep2_kernel<<<16400, 256, 0, stream>>>(x, s, s2, wsq, xp, outscale);
    conv_mfma9_kernel<<<dim3(8, 8, 16), 256, DLDS9, stream>>>(wt, xp, outscale,
                                                              out);
  } else {
    prep2_kernel<<<16400, 256, 0, stream>>>(x, s, s2, wsq, xp, outscale);
    conv_mfma_kernel<<<dim3(16, 8, 16), 256, 0, stream>>>(x, weight, s,
                                                          outscale, out);
  }
}

// Round 13
// 320.919 us; speedup vs baseline: 1.0584x; 1.0584x over previous
//
#include <hip/hip_runtime.h>
#include <math.h>

#define B 16
#define CIN 512
#define COUT 512
#define SDIM 512
#define H 64
#define W 64

typedef short s16x8 __attribute__((ext_vector_type(8)));
typedef float f32x4 __attribute__((ext_vector_type(4)));
typedef float f32x16 __attribute__((ext_vector_type(16)));

__device__ __constant__ float LIN_SCALE  = 0.04419417382415922f;   // 1/sqrt(512)
__device__ __constant__ float CONV_SCALE = 0.014731391274719742f;  // 1/sqrt(512*9)

__device__ __forceinline__ ushort f2bf(float f) {
  unsigned u = __float_as_uint(f);
  return (ushort)((u + 0x7FFFu + ((u >> 16) & 1u)) >> 16);  // RNE
}

#define GLOAD16(g, l)                                           \
  __builtin_amdgcn_global_load_lds(                             \
      (const __attribute__((address_space(1))) unsigned*)(g),   \
      (__attribute__((address_space(3))) unsigned*)(l), 16, 0, 0)

// ---------------------------------------------------------------------------
// K1: style modulation only. grid = B, block = 512. s[b,ci], s2 = s*s.
// ---------------------------------------------------------------------------
__global__ __launch_bounds__(512) void style_mod_kernel(
    const float* __restrict__ style, const float* __restrict__ style_w,
    const float* __restrict__ style_b, float* __restrict__ s,
    float* __restrict__ s2) {
  const int b = blockIdx.x;
  const int ci = threadIdx.x;
  __shared__ float st[SDIM];
  st[ci] = style[b * SDIM + ci];
  __syncthreads();

  const float4* wr = reinterpret_cast<const float4*>(style_w + (size_t)ci * SDIM);
  float acc = 0.f;
#pragma unroll 4
  for (int k = 0; k < SDIM / 4; ++k) {
    float4 wv = wr[k];
    acc += st[4 * k + 0] * wv.x + st[4 * k + 1] * wv.y +
           st[4 * k + 2] * wv.z + st[4 * k + 3] * wv.w;
  }
  float v = acc * LIN_SCALE + style_b[ci];
  s[b * CIN + ci] = v;
  s2[b * CIN + ci] = v * v;
}

// ---------------------------------------------------------------------------
// K2 (fat pack): blocks 0..511 pack_w (+wsq), ci-PAIR per thread;
//                blocks 512..16895 pack_x (s folded, CB16 octet-major).
// Weight traffic overlaps x traffic in one launch; no internal dependencies.
// wt: wt[chunk32][cb8][j9][oct2][co64][8ci] bf16
//   ushort strides: chunk 73728, cb 9216, j 1024, oct 512, co 8
// xp: xp[b][chunk32][oct2][gr64][col64][8ci] bf16
//   ushort strides: b 2097152, chunk 65536, oct 32768, gr 512, col 8
// ---------------------------------------------------------------------------
__global__ __launch_bounds__(256) void pack_kernel(
    const float* __restrict__ w, const float* __restrict__ x,
    const float* __restrict__ smod, ushort* __restrict__ wt,
    float* __restrict__ wsq, ushort* __restrict__ xp) {
  const int tid = threadIdx.x;
  if (blockIdx.x < 512) {
    const int u = blockIdx.x * 256 + tid;  // 131072 units
    const int e = u & 7;                   // ci-pair index (ci = 2e)
    const int chunk = (u >> 3) & 31;
    const int co = u >> 8;
    const float2* wp = (const float2*)(
        w + ((size_t)co * 512 + chunk * 16 + e * 2) * 9);
    float wv[18];
#pragma unroll
    for (int i = 0; i < 9; ++i) {
      float2 v = wp[i];
      wv[2 * i] = v.x;
      wv[2 * i + 1] = v.y;
    }
    {
      float q0 = 0.f, q1 = 0.f;
#pragma unroll
      for (int k = 0; k < 9; ++k) {
        q0 += wv[k] * wv[k];
        q1 += wv[9 + k] * wv[9 + k];
      }
      *(float2*)(wsq + (size_t)co * 512 + chunk * 16 + e * 2) =
          make_float2(q0, q1);
    }
    const int cb = co >> 6, co64 = co & 63;
    ushort* dst = wt + (size_t)chunk * 73728 + (size_t)cb * 9216 +
                  (size_t)(e >> 2) * 512 + (size_t)co64 * 8 + (e & 3) * 2;
#pragma unroll
    for (int j = 0; j < 9; ++j) {
      unsigned pk = (unsigned)f2bf(wv[j]) | ((unsigned)f2bf(wv[9 + j]) << 16);
      *(unsigned*)(dst + (size_t)j * 1024) = pk;
    }
  } else {
    const int blk = blockIdx.x - 512;  // 0..16383
    const int gr = blk & 63, cp = (blk >> 6) & 15, b = blk >> 10;
    __shared__ float xt[32][65];
    __shared__ float sm[32];
    if (tid < 32) sm[tid] = smod[b * 512 + cp * 32 + tid];
    {
      const int ci = tid >> 3, cq = tid & 7;
      const float4* rp = (const float4*)(
          x + (((size_t)b * 512 + cp * 32 + ci) * 64 + gr) * 64 + cq * 8);
      float4 a = rp[0], c2 = rp[1];
      float* row = &xt[ci][cq * 8];
      row[0] = a.x; row[1] = a.y; row[2] = a.z; row[3] = a.w;
      row[4] = c2.x; row[5] = c2.y; row[6] = c2.z; row[7] = c2.w;
    }
    __syncthreads();
    const int c = tid & 63, o = tid >> 6;  // col, ci-octet-of-32 (0..3)
    s16x8 p;
#pragma unroll
    for (int i = 0; i < 8; ++i)
      p[i] = (short)f2bf(xt[o * 8 + i][c] * sm[o * 8 + i]);
    const int chunk = cp * 2 + (o >> 1), oct = o & 1;
    *(s16x8*)(xp + (size_t)b * 2097152 + (size_t)chunk * 65536 +
              oct * 32768 + gr * 512 + c * 8) = p;
  }
}

// ---------------------------------------------------------------------------
// Kernel 9 (main loop identical to proven R10/R12 242us kernel); the dcoef
// (outscale) is now computed INLINE in the epilogue: per block, 64 values
// osc[co] = conv_scale * rsqrt(conv_scale^2 * dot(s2[b,:], wsq[co,:]) + 1e-8)
// via 4 threads/co (f32x4 partial dots + shfl_xor 4-lane reduce) in reused
// LDS. Removes the separate dcoef kernel + one dependency stage.
// ---------------------------------------------------------------------------
#define CBUF_WS 18432
#define CBUF_XS 21120
#define XS_BASE 36864
#define DLDS9 79104

__global__ __launch_bounds__(256, 2) void conv_mfma9_kernel(
    const ushort* __restrict__ wt, const ushort* __restrict__ xp,
    const float* __restrict__ wsq, const float* __restrict__ s2,
    float* __restrict__ out) {
  extern __shared__ char smem[];

  const int tid = threadIdx.x;
  const int hb = blockIdx.x;  // 0..7
  const int cb = blockIdx.y;  // 0..7
  const int b  = blockIdx.z;  // 0..15
  const int h0 = hb * 8, co0 = cb * 64;
  const int lane = tid & 63, wid = tid >> 6;  // 4 waves
  const int l31 = lane & 31, hi = lane >> 5;

  {
    s16x8* p = (s16x8*)(smem + XS_BASE);
    for (int e = tid; e < 2640; e += 256) p[e] = (s16x8)0;
  }

  f32x16 acc[2][2][2];
#pragma unroll
  for (int rr = 0; rr < 2; ++rr)
#pragma unroll
    for (int mt = 0; mt < 2; ++mt)
#pragma unroll
      for (int nt = 0; nt < 2; ++nt) acc[rr][mt][nt] = (f32x16)0.f;

  int aoff[2];
#pragma unroll
  for (int mt = 0; mt < 2; ++mt)
    aoff[mt] = hi * 1024 + (mt * 32 + l31) * 16;
  int boff[3][2];
#pragma unroll
  for (int kw = 0; kw < 3; ++kw)
#pragma unroll
    for (int nt = 0; nt < 2; ++nt)
      boff[kw][nt] = hi * 10560 + (nt * 32 + l31 + kw) * 16;

  const char* wsrc0 = (const char*)wt + (size_t)cb * 18432;
  const char* xsrc0 = (const char*)xp + (size_t)b * 4194304;

  auto stage = [&](int chunk, int buf) {
    const char* wsrc = wsrc0 + (size_t)chunk * 147456;
    const char* xsrc = xsrc0 + (size_t)chunk * 131072;
    char* wd = smem + buf * CBUF_WS;
    char* xd = smem + XS_BASE + buf * CBUF_XS;
#pragma unroll
    for (int p = 0; p < 4; ++p)
      GLOAD16(wsrc + p * 4096 + tid * 16, wd + p * 4096 + tid * 16);
    if (tid < 128)
      GLOAD16(wsrc + 16384 + tid * 16, wd + 16384 + tid * 16);
#pragma unroll
    for (int p = 0; p < 5; ++p) {
      int e = p * 4 + wid;  // 0..19 = (oct, row)
      int oct = (e >= 10) ? 1 : 0;
      int r = e - oct * 10;
      int gr = h0 - 1 + r;
      if ((unsigned)gr < 64u)
        GLOAD16(xsrc + oct * 65536 + gr * 1024 + lane * 16,
                xd + oct * 10560 + r * 1056 + 16 + lane * 16);
    }
  };

  auto compute = [&](int buf) {
    const char* wb2 = smem + buf * CBUF_WS;
    const char* xb2 = smem + XS_BASE + buf * CBUF_XS + 2 * wid * 1056;
#pragma unroll
    for (int kw = 0; kw < 3; ++kw) {
      s16x8 bf[4][2];  // rows 2wid..2wid+3, cached across kh
#pragma unroll
      for (int q = 0; q < 4; ++q)
#pragma unroll
        for (int nt = 0; nt < 2; ++nt)
          bf[q][nt] = *(const s16x8*)(xb2 + q * 1056 + boff[kw][nt]);
#pragma unroll
      for (int kh = 0; kh < 3; ++kh) {
        const char* wj = wb2 + (kh * 3 + kw) * 2048;
        s16x8 af0 = *(const s16x8*)(wj + aoff[0]);
        s16x8 af1 = *(const s16x8*)(wj + aoff[1]);
#pragma unroll
        for (int rr = 0; rr < 2; ++rr)
#pragma unroll
          for (int nt = 0; nt < 2; ++nt) {
            acc[rr][0][nt] = __builtin_amdgcn_mfma_f32_32x32x16_bf16(
                af0, bf[rr + kh][nt], acc[rr][0][nt], 0, 0, 0);
            acc[rr][1][nt] = __builtin_amdgcn_mfma_f32_32x32x16_bf16(
                af1, bf[rr + kh][nt], acc[rr][1][nt], 0, 0, 0);
          }
      }
    }
  };

  __syncthreads();  // zeros visible
  stage(0, 0);

  for (int c = 0; c < 32; ++c) {
    const int buf = c & 1;
    __syncthreads();  // drains stage(c) (issued a full chunk ago -> ~free);
                      // also: all waves done reading buf^1 (chunk c-1)
    if (c + 1 < 32) stage(c + 1, buf ^ 1);
    compute(buf);
  }

  // ---- inline dcoef: osc[co64] for this block's 64 cos ----
  __syncthreads();  // all compute done; smem reusable
  float* s2sh = (float*)smem;           // 512 floats
  float* oscsh = (float*)(smem + 2048); // 64 floats
  s2sh[tid] = s2[b * CIN + tid];
  s2sh[tid + 256] = s2[b * CIN + tid + 256];
  __syncthreads();
  {
    const int co = tid >> 2, q = tid & 3;
    const float4* wr = (const float4*)(wsq + (size_t)(co0 + co) * CIN);
    float a = 0.f;
#pragma unroll
    for (int k = 0; k < 32; ++k) {
      float4 v = wr[q + k * 4];
      const float* sp = s2sh + (q + k * 4) * 4;
      a += v.x * sp[0] + v.y * sp[1] + v.z * sp[2] + v.w * sp[3];
    }
    a += __shfl_xor(a, 1);
    a += __shfl_xor(a, 2);
    if (q == 0)
      oscsh[co] = CONV_SCALE * rsqrtf(a * CONV_SCALE * CONV_SCALE + 1e-8f);
  }
  __syncthreads();

  // epilogue: D col(px)=l31, row(co)=(reg&3)+8*(reg>>2)+4*hi
#pragma unroll
  for (int mt = 0; mt < 2; ++mt) {
#pragma unroll
    for (int reg = 0; reg < 16; ++reg) {
      const int row = (reg & 3) + 8 * (reg >> 2) + 4 * hi;
      const int co = co0 + mt * 32 + row;
      const float osc = oscsh[mt * 32 + row];
      float* obase = out + ((size_t)b * COUT + co) * H * W;
#pragma unroll
      for (int rr = 0; rr < 2; ++rr) {
        const int h = h0 + 2 * wid + rr;
#pragma unroll
        for (int nt = 0; nt < 2; ++nt)
          obase[h * W + nt * 32 + l31] = acc[rr][mt][nt][reg] * osc;
      }
    }
  }
}

// ---------------------------------------------------------------------------
// Fallback path kernels (only if hipFuncSetAttribute fails / ws too small):
// standalone dcoef + R2-style packless conv (~630us, proven).
// ---------------------------------------------------------------------------
__global__ __launch_bounds__(512) void dcoef_kernel(
    const float* __restrict__ s2, const float* __restrict__ wsq,
    float* __restrict__ outscale) {
  const int b = blockIdx.x;
  const int co = threadIdx.x;
  __shared__ float sh[CIN];
  sh[co] = s2[b * CIN + co];
  __syncthreads();

  const float4* wr = reinterpret_cast<const float4*>(wsq + (size_t)co * CIN);
  float acc = 0.f;
#pragma unroll 4
  for (int k = 0; k < CIN / 4; ++k) {
    float4 wv = wr[k];
    acc += sh[4 * k + 0] * wv.x + sh[4 * k + 1] * wv.y +
           sh[4 * k + 2] * wv.z + sh[4 * k + 3] * wv.w;
  }
  float d = rsqrtf(acc * CONV_SCALE * CONV_SCALE + 1e-8f);
  outscale[b * COUT + co] = d * CONV_SCALE;
}

__global__ __launch_bounds__(256, 2) void conv_mfma_kernel(
    const float* __restrict__ x, const float* __restrict__ weight,
    const float* __restrict__ s, const float* __restrict__ outscale,
    float* __restrict__ out) {
  __shared__ ushort xs[6][66][32];
  __shared__ ushort ws[9][64][32];

  const int tid = threadIdx.x;
  const int hb = blockIdx.x;
  const int cb = blockIdx.y;
  const int b  = blockIdx.z;
  const int h0 = hb * 4;
  const int co0 = cb * 64;
  const int lane = tid & 63;
  const int wid = tid >> 6;
  const int l15 = lane & 15;
  const int l4  = lane >> 4;

  f32x4 acc[4][4];
#pragma unroll
  for (int mt = 0; mt < 4; ++mt)
#pragma unroll
    for (int nt = 0; nt < 4; ++nt) acc[mt][nt] = (f32x4)0.f;

  const int wq = tid & 3;
  const int wco = tid >> 2;

  for (int c0 = 0; c0 < CIN; c0 += 32) {
    {
      const float4* wp = reinterpret_cast<const float4*>(
          weight + ((size_t)(co0 + wco) * CIN + c0 + wq * 8) * 9);
      float wv[72];
#pragma unroll
      for (int t = 0; t < 18; ++t) {
        float4 v = wp[t];
        wv[4 * t + 0] = v.x; wv[4 * t + 1] = v.y;
        wv[4 * t + 2] = v.z; wv[4 * t + 3] = v.w;
      }
      float sv[8];
#pragma unroll
      for (int i = 0; i < 8; ++i) sv[i] = s[b * CIN + c0 + wq * 8 + i];
#pragma unroll
      for (int j = 0; j < 9; ++j) {
        s16x8 p;
#pragma unroll
        for (int i = 0; i < 8; ++i)
          p[i] = (short)f2bf(wv[i * 9 + j] * sv[i]);
        *reinterpret_cast<s16x8*>(&ws[j][wco][wq * 8]) = p;
      }
    }
#pragma unroll
    for (int it = 0; it < 7; ++it) {
      int e = tid + it * 256;
      if (e < 6 * 66 * 4) {
        int q = e & 3;
        int t2 = e >> 2;
        int cc = t2 % 66;
        int r = t2 / 66;
        int gr = h0 - 1 + r;
        int gc = cc - 1;
        s16x8 p;
        if ((unsigned)gr < H && (unsigned)gc < W) {
          const float* xp2 =
              x + (((size_t)b * CIN + c0 + q * 8) * H + gr) * W + gc;
#pragma unroll
          for (int i = 0; i < 8; ++i) p[i] = (short)f2bf(xp2[(size_t)i * H * W]);
        } else {
#pragma unroll
          for (int i = 0; i < 8; ++i) p[i] = 0;
        }
        *reinterpret_cast<s16x8*>(&xs[r][cc][q * 8]) = p;
      }
    }
    __syncthreads();

#pragma unroll
    for (int kh = 0; kh < 3; ++kh) {
#pragma unroll
      for (int kw = 0; kw < 3; ++kw) {
        const int j = kh * 3 + kw;
        s16x8 af[4], bf[4];
#pragma unroll
        for (int mt = 0; mt < 4; ++mt)
          af[mt] = *reinterpret_cast<const s16x8*>(
              &ws[j][mt * 16 + l15][l4 * 8]);
#pragma unroll
        for (int nt = 0; nt < 4; ++nt)
          bf[nt] = *reinterpret_cast<const s16x8*>(
              &xs[wid + kh][nt * 16 + l15 + kw][l4 * 8]);
#pragma unroll
        for (int mt = 0; mt < 4; ++mt)
#pragma unroll
          for (int nt = 0; nt < 4; ++nt)
            acc[mt][nt] = __builtin_amdgcn_mfma_f32_16x16x32_bf16(
                af[mt], bf[nt], acc[mt][nt], 0, 0, 0);
      }
    }
    __syncthreads();
  }

  const int h = h0 + wid;
#pragma unroll
  for (int mt = 0; mt < 4; ++mt) {
#pragma unroll
    for (int r = 0; r < 4; ++r) {
      const int co = co0 + mt * 16 + l4 * 4 + r;
      const float osc = outscale[b * COUT + co];
      float* orow = out + (((size_t)b * COUT + co) * H + h) * W;
#pragma unroll
      for (int nt = 0; nt < 4; ++nt)
        orow[nt * 16 + l15] = acc[mt][nt][r] * osc;
    }
  }
}

// ---------------------------------------------------------------------------
extern "C" void kernel_launch(void* const* d_in, const int* in_sizes, int n_in,
                              void* d_out, int out_size, void* d_ws,
                              size_t ws_size, hipStream_t stream) {
  const float* x = (const float*)d_in[0];
  const float* style = (const float*)d_in[1];
  const float* weight = (const float*)d_in[2];
  const float* style_w = (const float*)d_in[3];
  const float* style_b = (const float*)d_in[4];
  float* out = (float*)d_out;

  // workspace layout (bytes):
  //   0        s        (32768)
  //   32768    s2       (32768)
  //   65536    wsq      (1048576)
  //   1114112  outscale (32768)   [fallback path only]
  //   1146880  wt       (4718592)   packed bf16 weights (CB16 octet-major)
  //   5865472  xp       (67108864)  packed bf16 x (s folded, CB16 octet-major)
  char* wsb = (char*)d_ws;
  float* s = (float*)(wsb + 0);
  float* s2 = (float*)(wsb + 32768);
  float* wsq = (float*)(wsb + 65536);
  float* outscale = (float*)(wsb + 1114112);
  ushort* wt = (ushort*)(wsb + 1146880);
  ushort* xp = (ushort*)(wsb + 5865472);
  const size_t NEED = 72974336;

  hipError_t attr_ok = hipFuncSetAttribute(
      reinterpret_cast<const void*>(conv_mfma9_kernel),
      hipFuncAttributeMaxDynamicSharedMemorySize, DLDS9);

  style_mod_kernel<<<B, 512, 0, stream>>>(style, style_w, style_b, s, s2);
  pack_kernel<<<16896, 256, 0, stream>>>(weight, x, s, wt, wsq, xp);

  if (attr_ok == hipSuccess && ws_size >= NEED) {
    conv_mfma9_kernel<<<dim3(8, 8, 16), 256, DLDS9, stream>>>(wt, xp, wsq, s2,
                                                              out);
  } else {
    dcoef_kernel<<<B, 512, 0, stream>>>(s2, wsq, outscale);
    conv_mfma_kernel<<<dim3(16, 8, 16), 256, 0, stream>>>(x, weight, s,
                                                          outscale, out);
  }
}

// Round 14
// 306.173 us; speedup vs baseline: 1.1094x; 1.0482x over previous
//
#include <hip/hip_runtime.h>
#include <math.h>

#define B 16
#define CIN 512
#define COUT 512
#define SDIM 512
#define H 64
#define W 64

typedef short s16x8 __attribute__((ext_vector_type(8)));
typedef float f32x4 __attribute__((ext_vector_type(4)));
typedef float f32x16 __attribute__((ext_vector_type(16)));

__device__ __constant__ float LIN_SCALE  = 0.04419417382415922f;   // 1/sqrt(512)
__device__ __constant__ float CONV_SCALE = 0.014731391274719742f;  // 1/sqrt(512*9)

__device__ __forceinline__ ushort f2bf(float f) {
  unsigned u = __float_as_uint(f);
  return (ushort)((u + 0x7FFFu + ((u >> 16) & 1u)) >> 16);  // RNE
}

#define GLOAD16(g, l)                                           \
  __builtin_amdgcn_global_load_lds(                             \
      (const __attribute__((address_space(1))) unsigned*)(g),   \
      (__attribute__((address_space(3))) unsigned*)(l), 16, 0, 0)

// ---------------------------------------------------------------------------
// K1: style modulation. grid = B, block = 512. s[b,ci], s2 = s*s.
// ---------------------------------------------------------------------------
__global__ __launch_bounds__(512) void style_mod_kernel(
    const float* __restrict__ style, const float* __restrict__ style_w,
    const float* __restrict__ style_b, float* __restrict__ s,
    float* __restrict__ s2) {
  const int b = blockIdx.x;
  const int ci = threadIdx.x;
  __shared__ float st[SDIM];
  st[ci] = style[b * SDIM + ci];
  __syncthreads();

  const float4* wr = reinterpret_cast<const float4*>(style_w + (size_t)ci * SDIM);
  float acc = 0.f;
#pragma unroll 4
  for (int k = 0; k < SDIM / 4; ++k) {
    float4 wv = wr[k];
    acc += st[4 * k + 0] * wv.x + st[4 * k + 1] * wv.y +
           st[4 * k + 2] * wv.z + st[4 * k + 3] * wv.w;
  }
  float v = acc * LIN_SCALE + style_b[ci];
  s[b * CIN + ci] = v;
  s2[b * CIN + ci] = v * v;
}

// ---------------------------------------------------------------------------
// K2 (fat pack): blocks 0..511 pack_w + INLINE dcoef (block blk = co blk;
//   wsq[co,:] lives entirely in this block -> osc[b,co] for all 16 b computed
//   here: LDS-shared wsq + 16thr/b partial dots + shfl_xor reduce);
//   blocks 512..16895 pack_x (s folded, CB16 octet-major).
// wt: wt[chunk32][cb8][j9][oct2][co64][8ci] bf16
//   ushort strides: chunk 73728, cb 9216, j 1024, oct 512, co 8
// xp: xp[b][chunk32][oct2][gr64][col64][8ci] bf16
//   ushort strides: b 2097152, chunk 65536, oct 32768, gr 512, col 8
// ---------------------------------------------------------------------------
__global__ __launch_bounds__(256) void pack_kernel(
    const float* __restrict__ w, const float* __restrict__ x,
    const float* __restrict__ smod, const float* __restrict__ s2,
    ushort* __restrict__ wt, ushort* __restrict__ xp,
    float* __restrict__ outscale) {
  const int tid = threadIdx.x;
  if (blockIdx.x < 512) {
    const int co = blockIdx.x;           // one co per block
    const int e = tid & 7;               // ci-pair index (ci = chunk*16+2e)
    const int chunk = tid >> 3;          // 0..31
    const int ci = chunk * 16 + e * 2;
    __shared__ float wsh[512];
    const float2* wp = (const float2*)(w + ((size_t)co * 512 + ci) * 9);
    float wv[18];
#pragma unroll
    for (int i = 0; i < 9; ++i) {
      float2 v = wp[i];
      wv[2 * i] = v.x;
      wv[2 * i + 1] = v.y;
    }
    {
      float q0 = 0.f, q1 = 0.f;
#pragma unroll
      for (int k = 0; k < 9; ++k) {
        q0 += wv[k] * wv[k];
        q1 += wv[9 + k] * wv[9 + k];
      }
      wsh[ci] = q0;
      wsh[ci + 1] = q1;
    }
    const int cb = co >> 6, co64 = co & 63;
    ushort* dst = wt + (size_t)chunk * 73728 + (size_t)cb * 9216 +
                  (size_t)(e >> 2) * 512 + (size_t)co64 * 8 + (e & 3) * 2;
#pragma unroll
    for (int j = 0; j < 9; ++j) {
      unsigned pk = (unsigned)f2bf(wv[j]) | ((unsigned)f2bf(wv[9 + j]) << 16);
      *(unsigned*)(dst + (size_t)j * 1024) = pk;
    }
    // ---- inline dcoef for this co, all 16 batches
    __syncthreads();
    const int bb = tid >> 4, seg = tid & 15;  // 16 threads per batch
    const float4* s2p = (const float4*)(s2 + (size_t)bb * CIN + seg * 32);
    const float4* wq4 = (const float4*)(wsh + seg * 32);
    float a = 0.f;
#pragma unroll
    for (int k = 0; k < 8; ++k) {
      float4 sv = s2p[k], qv = wq4[k];
      a += sv.x * qv.x + sv.y * qv.y + sv.z * qv.z + sv.w * qv.w;
    }
    a += __shfl_xor(a, 1);
    a += __shfl_xor(a, 2);
    a += __shfl_xor(a, 4);
    a += __shfl_xor(a, 8);
    if (seg == 0)
      outscale[bb * COUT + co] =
          CONV_SCALE * rsqrtf(a * CONV_SCALE * CONV_SCALE + 1e-8f);
  } else {
    const int blk = blockIdx.x - 512;  // 0..16383
    const int gr = blk & 63, cp = (blk >> 6) & 15, b = blk >> 10;
    __shared__ float xt[32][65];
    __shared__ float sm[32];
    if (tid < 32) sm[tid] = smod[b * 512 + cp * 32 + tid];
    {
      const int ci = tid >> 3, cq = tid & 7;
      const float4* rp = (const float4*)(
          x + (((size_t)b * 512 + cp * 32 + ci) * 64 + gr) * 64 + cq * 8);
      float4 a = rp[0], c2 = rp[1];
      float* row = &xt[ci][cq * 8];
      row[0] = a.x; row[1] = a.y; row[2] = a.z; row[3] = a.w;
      row[4] = c2.x; row[5] = c2.y; row[6] = c2.z; row[7] = c2.w;
    }
    __syncthreads();
    const int c = tid & 63, o = tid >> 6;  // col, ci-octet-of-32 (0..3)
    s16x8 p;
#pragma unroll
    for (int i = 0; i < 8; ++i)
      p[i] = (short)f2bf(xt[o * 8 + i][c] * sm[o * 8 + i]);
    const int chunk = cp * 2 + (o >> 1), oct = o & 1;
    *(s16x8*)(xp + (size_t)b * 2097152 + (size_t)chunk * 65536 +
              oct * 32768 + gr * 512 + c * 8) = p;
  }
}

// ---------------------------------------------------------------------------
// Kernel 9 (reverted to proven R10/R12 242us version): dbuf-prefetch
// 32x32x16 MFMA conv, CB=16, 2 blocks/CU, octet-major dense LDS (0 confl).
// Epilogue reads precomputed outscale.
// ---------------------------------------------------------------------------
#define CBUF_WS 18432
#define CBUF_XS 21120
#define XS_BASE 36864
#define DLDS9 79104

__global__ __launch_bounds__(256, 2) void conv_mfma9_kernel(
    const ushort* __restrict__ wt, const ushort* __restrict__ xp,
    const float* __restrict__ outscale, float* __restrict__ out) {
  extern __shared__ char smem[];

  const int tid = threadIdx.x;
  const int hb = blockIdx.x;  // 0..7
  const int cb = blockIdx.y;  // 0..7
  const int b  = blockIdx.z;  // 0..15
  const int h0 = hb * 8, co0 = cb * 64;
  const int lane = tid & 63, wid = tid >> 6;  // 4 waves
  const int l31 = lane & 31, hi = lane >> 5;

  {
    s16x8* p = (s16x8*)(smem + XS_BASE);
    for (int e = tid; e < 2640; e += 256) p[e] = (s16x8)0;
  }

  f32x16 acc[2][2][2];
#pragma unroll
  for (int rr = 0; rr < 2; ++rr)
#pragma unroll
    for (int mt = 0; mt < 2; ++mt)
#pragma unroll
      for (int nt = 0; nt < 2; ++nt) acc[rr][mt][nt] = (f32x16)0.f;

  int aoff[2];
#pragma unroll
  for (int mt = 0; mt < 2; ++mt)
    aoff[mt] = hi * 1024 + (mt * 32 + l31) * 16;
  int boff[3][2];
#pragma unroll
  for (int kw = 0; kw < 3; ++kw)
#pragma unroll
    for (int nt = 0; nt < 2; ++nt)
      boff[kw][nt] = hi * 10560 + (nt * 32 + l31 + kw) * 16;

  const char* wsrc0 = (const char*)wt + (size_t)cb * 18432;
  const char* xsrc0 = (const char*)xp + (size_t)b * 4194304;

  auto stage = [&](int chunk, int buf) {
    const char* wsrc = wsrc0 + (size_t)chunk * 147456;
    const char* xsrc = xsrc0 + (size_t)chunk * 131072;
    char* wd = smem + buf * CBUF_WS;
    char* xd = smem + XS_BASE + buf * CBUF_XS;
#pragma unroll
    for (int p = 0; p < 4; ++p)
      GLOAD16(wsrc + p * 4096 + tid * 16, wd + p * 4096 + tid * 16);
    if (tid < 128)
      GLOAD16(wsrc + 16384 + tid * 16, wd + 16384 + tid * 16);
#pragma unroll
    for (int p = 0; p < 5; ++p) {
      int e = p * 4 + wid;  // 0..19 = (oct, row)
      int oct = (e >= 10) ? 1 : 0;
      int r = e - oct * 10;
      int gr = h0 - 1 + r;
      if ((unsigned)gr < 64u)
        GLOAD16(xsrc + oct * 65536 + gr * 1024 + lane * 16,
                xd + oct * 10560 + r * 1056 + 16 + lane * 16);
    }
  };

  auto compute = [&](int buf) {
    const char* wb2 = smem + buf * CBUF_WS;
    const char* xb2 = smem + XS_BASE + buf * CBUF_XS + 2 * wid * 1056;
#pragma unroll
    for (int kw = 0; kw < 3; ++kw) {
      s16x8 bf[4][2];  // rows 2wid..2wid+3, cached across kh
#pragma unroll
      for (int q = 0; q < 4; ++q)
#pragma unroll
        for (int nt = 0; nt < 2; ++nt)
          bf[q][nt] = *(const s16x8*)(xb2 + q * 1056 + boff[kw][nt]);
#pragma unroll
      for (int kh = 0; kh < 3; ++kh) {
        const char* wj = wb2 + (kh * 3 + kw) * 2048;
        s16x8 af0 = *(const s16x8*)(wj + aoff[0]);
        s16x8 af1 = *(const s16x8*)(wj + aoff[1]);
#pragma unroll
        for (int rr = 0; rr < 2; ++rr)
#pragma unroll
          for (int nt = 0; nt < 2; ++nt) {
            acc[rr][0][nt] = __builtin_amdgcn_mfma_f32_32x32x16_bf16(
                af0, bf[rr + kh][nt], acc[rr][0][nt], 0, 0, 0);
            acc[rr][1][nt] = __builtin_amdgcn_mfma_f32_32x32x16_bf16(
                af1, bf[rr + kh][nt], acc[rr][1][nt], 0, 0, 0);
          }
      }
    }
  };

  __syncthreads();  // zeros visible
  stage(0, 0);

  for (int c = 0; c < 32; ++c) {
    const int buf = c & 1;
    __syncthreads();  // drains stage(c) (issued a full chunk ago -> ~free);
                      // also: all waves done reading buf^1 (chunk c-1)
    if (c + 1 < 32) stage(c + 1, buf ^ 1);
    compute(buf);
  }

  // epilogue: D col(px)=l31, row(co)=(reg&3)+8*(reg>>2)+4*hi
#pragma unroll
  for (int mt = 0; mt < 2; ++mt) {
#pragma unroll
    for (int reg = 0; reg < 16; ++reg) {
      const int row = (reg & 3) + 8 * (reg >> 2) + 4 * hi;
      const int co = co0 + mt * 32 + row;
      const float osc = outscale[b * COUT + co];
      float* obase = out + ((size_t)b * COUT + co) * H * W;
#pragma unroll
      for (int rr = 0; rr < 2; ++rr) {
        const int h = h0 + 2 * wid + rr;
#pragma unroll
        for (int nt = 0; nt < 2; ++nt)
          obase[h * W + nt * 32 + l31] = acc[rr][mt][nt][reg] * osc;
      }
    }
  }
}

// ---------------------------------------------------------------------------
// Fallback path kernels (only if hipFuncSetAttribute fails / ws too small):
// wsq + dcoef + R2-style packless conv (~630us, proven).
// ---------------------------------------------------------------------------
__global__ __launch_bounds__(256) void wsq_kernel(
    const float* __restrict__ weight, float* __restrict__ wsq) {
  const int i = blockIdx.x * blockDim.x + threadIdx.x;
  if (i >= COUT * CIN) return;
  const float* p = weight + (size_t)i * 9;
  float a = 0.f;
#pragma unroll
  for (int k = 0; k < 9; ++k) {
    float v = p[k];
    a += v * v;
  }
  wsq[i] = a;
}

__global__ __launch_bounds__(512) void dcoef_kernel(
    const float* __restrict__ s2, const float* __restrict__ wsq,
    float* __restrict__ outscale) {
  const int b = blockIdx.x;
  const int co = threadIdx.x;
  __shared__ float sh[CIN];
  sh[co] = s2[b * CIN + co];
  __syncthreads();

  const float4* wr = reinterpret_cast<const float4*>(wsq + (size_t)co * CIN);
  float acc = 0.f;
#pragma unroll 4
  for (int k = 0; k < CIN / 4; ++k) {
    float4 wv = wr[k];
    acc += sh[4 * k + 0] * wv.x + sh[4 * k + 1] * wv.y +
           sh[4 * k + 2] * wv.z + sh[4 * k + 3] * wv.w;
  }
  float d = rsqrtf(acc * CONV_SCALE * CONV_SCALE + 1e-8f);
  outscale[b * COUT + co] = d * CONV_SCALE;
}

__global__ __launch_bounds__(256, 2) void conv_mfma_kernel(
    const float* __restrict__ x, const float* __restrict__ weight,
    const float* __restrict__ s, const float* __restrict__ outscale,
    float* __restrict__ out) {
  __shared__ ushort xs[6][66][32];
  __shared__ ushort ws[9][64][32];

  const int tid = threadIdx.x;
  const int hb = blockIdx.x;
  const int cb = blockIdx.y;
  const int b  = blockIdx.z;
  const int h0 = hb * 4;
  const int co0 = cb * 64;
  const int lane = tid & 63;
  const int wid = tid >> 6;
  const int l15 = lane & 15;
  const int l4  = lane >> 4;

  f32x4 acc[4][4];
#pragma unroll
  for (int mt = 0; mt < 4; ++mt)
#pragma unroll
    for (int nt = 0; nt < 4; ++nt) acc[mt][nt] = (f32x4)0.f;

  const int wq = tid & 3;
  const int wco = tid >> 2;

  for (int c0 = 0; c0 < CIN; c0 += 32) {
    {
      const float4* wp = reinterpret_cast<const float4*>(
          weight + ((size_t)(co0 + wco) * CIN + c0 + wq * 8) * 9);
      float wv[72];
#pragma unroll
      for (int t = 0; t < 18; ++t) {
        float4 v = wp[t];
        wv[4 * t + 0] = v.x; wv[4 * t + 1] = v.y;
        wv[4 * t + 2] = v.z; wv[4 * t + 3] = v.w;
      }
      float sv[8];
#pragma unroll
      for (int i = 0; i < 8; ++i) sv[i] = s[b * CIN + c0 + wq * 8 + i];
#pragma unroll
      for (int j = 0; j < 9; ++j) {
        s16x8 p;
#pragma unroll
        for (int i = 0; i < 8; ++i)
          p[i] = (short)f2bf(wv[i * 9 + j] * sv[i]);
        *reinterpret_cast<s16x8*>(&ws[j][wco][wq * 8]) = p;
      }
    }
#pragma unroll
    for (int it = 0; it < 7; ++it) {
      int e = tid + it * 256;
      if (e < 6 * 66 * 4) {
        int q = e & 3;
        int t2 = e >> 2;
        int cc = t2 % 66;
        int r = t2 / 66;
        int gr = h0 - 1 + r;
        int gc = cc - 1;
        s16x8 p;
        if ((unsigned)gr < H && (unsigned)gc < W) {
          const float* xp2 =
              x + (((size_t)b * CIN + c0 + q * 8) * H + gr) * W + gc;
#pragma unroll
          for (int i = 0; i < 8; ++i) p[i] = (short)f2bf(xp2[(size_t)i * H * W]);
        } else {
#pragma unroll
          for (int i = 0; i < 8; ++i) p[i] = 0;
        }
        *reinterpret_cast<s16x8*>(&xs[r][cc][q * 8]) = p;
      }
    }
    __syncthreads();

#pragma unroll
    for (int kh = 0; kh < 3; ++kh) {
#pragma unroll
      for (int kw = 0; kw < 3; ++kw) {
        const int j = kh * 3 + kw;
        s16x8 af[4], bf[4];
#pragma unroll
        for (int mt = 0; mt < 4; ++mt)
          af[mt] = *reinterpret_cast<const s16x8*>(
              &ws[j][mt * 16 + l15][l4 * 8]);
#pragma unroll
        for (int nt = 0; nt < 4; ++nt)
          bf[nt] = *reinterpret_cast<const s16x8*>(
              &xs[wid + kh][nt * 16 + l15 + kw][l4 * 8]);
#pragma unroll
        for (int mt = 0; mt < 4; ++mt)
#pragma unroll
          for (int nt = 0; nt < 4; ++nt)
            acc[mt][nt] = __builtin_amdgcn_mfma_f32_16x16x32_bf16(
                af[mt], bf[nt], acc[mt][nt], 0, 0, 0);
      }
    }
    __syncthreads();
  }

  const int h = h0 + wid;
#pragma unroll
  for (int mt = 0; mt < 4; ++mt) {
#pragma unroll
    for (int r = 0; r < 4; ++r) {
      const int co = co0 + mt * 16 + l4 * 4 + r;
      const float osc = outscale[b * COUT + co];
      float* orow = out + (((size_t)b * COUT + co) * H + h) * W;
#pragma unroll
      for (int nt = 0; nt < 4; ++nt)
        orow[nt * 16 + l15] = acc[mt][nt][r] * osc;
    }
  }
}

// ---------------------------------------------------------------------------
extern "C" void kernel_launch(void* const* d_in, const int* in_sizes, int n_in,
                              void* d_out, int out_size, void* d_ws,
                              size_t ws_size, hipStream_t stream) {
  const float* x = (const float*)d_in[0];
  const float* style = (const float*)d_in[1];
  const float* weight = (const float*)d_in[2];
  const float* style_w = (const float*)d_in[3];
  const float* style_b = (const float*)d_in[4];
  float* out = (float*)d_out;

  // workspace layout (bytes):
  //   0        s        (32768)
  //   32768    s2       (32768)
  //   65536    wsq      (1048576)   [fallback path only]
  //   1114112  outscale (32768)
  //   1146880  wt       (4718592)   packed bf16 weights (CB16 octet-major)
  //   5865472  xp       (67108864)  packed bf16 x (s folded, CB16 octet-major)
  char* wsb = (char*)d_ws;
  float* s = (float*)(wsb + 0);
  float* s2 = (float*)(wsb + 32768);
  float* wsq = (float*)(wsb + 65536);
  float* outscale = (float*)(wsb + 1114112);
  ushort* wt = (ushort*)(wsb + 1146880);
  ushort* xp = (ushort*)(wsb + 5865472);
  const size_t NEED = 72974336;

  hipError_t attr_ok = hipFuncSetAttribute(
      reinterpret_cast<const void*>(conv_mfma9_kernel),
      hipFuncAttributeMaxDynamicSharedMemorySize, DLDS9);

  style_mod_kernel<<<B, 512, 0, stream>>>(style, style_w, style_b, s, s2);

  if (attr_ok == hipSuccess && ws_size >= NEED) {
    pack_kernel<<<16896, 256, 0, stream>>>(weight, x, s, s2, wt, xp, outscale);
    conv_mfma9_kernel<<<dim3(8, 8, 16), 256, DLDS9, stream>>>(wt, xp, outscale,
                                                              out);
  } else {
    wsq_kernel<<<(COUT * CIN + 255) / 256, 256, 0, stream>>>(weight, wsq);
    dcoef_kernel<<<B, 512, 0, stream>>>(s2, wsq, outscale);
    conv_mfma_kernel<<<dim3(16, 8, 16), 256, 0, stream>>>(x, weight, s,
                                                          outscale, out);
  }
}